// Round 26
// baseline (70.087 us; speedup 1.0000x reference)
//
#include <hip/hip_runtime.h>

#define FDIM  256
#define H1D   256
#define H2D   128
#define BATCH 4096

typedef _Float16 half2v __attribute__((ext_vector_type(2)));

#define ROW_U32    132                       // 64 (A,C) u32 pairs + 4 pad (16B-aligned rows)
#define NROWS      257
#define DLDS_U32   (NROWS * ROW_U32)         // 33,924
#define DLDS_BYTES (DLDS_U32 * 4)            // 135,696

#define SEG    8
#define SEGLEN 32

union U32H2 { unsigned u; half2v h; };
union H16U { _Float16 h; unsigned short u; };

// DPP helpers: cross-lane on the VALU pipe (not DS). bound_ctrl=true -> 0 fill.
#define DPP_ADD_F(v, ctrl)                                                   \
    ((v) + __int_as_float(__builtin_amdgcn_update_dpp(                       \
               0, __float_as_int(v), (ctrl), 0xf, 0xf, true)))
#define DPP_GET_I(x, ctrl)                                                   \
    __builtin_amdgcn_update_dpp(0, (int)(x), (ctrl), 0xf, 0xf, true)
// ctrl: quad_perm[1,0,3,2]=0xB1 (xor1), [2,3,0,1]=0x4E (xor2),
//       row_ror:4=0x124, row_ror:8=0x128 (rotation -> total in ALL lanes).

// ---------------------------------------------------------------------------
// Fused build+eval (R25 + W2 register-replay):
// Pass A FULLY unrolled, caching its 32 data-dependent W2 loads in w2r[32]
// (static indexing -> registers). Pass B becomes a pure VALU/LDS replay —
// no global loads at all — halving W2 HBM traffic (64->32 MB) and deleting
// the second dependent-load chain. E0 (strided x reads) stays before Pass B
// so its global latency overlaps Pass B's compute.
// ---------------------------------------------------------------------------
__global__ __launch_bounds__(1024, 4) void coxnam_fused(
    const float* __restrict__ W1, const float* __restrict__ b1,
    const float* __restrict__ W2, const float* __restrict__ b2,
    const float* __restrict__ x,  const float* __restrict__ W3,
    float* __restrict__ partial) {
    extern __shared__ unsigned rlds[];          // 33,924 u32 = 132.5 KB
    __shared__ float t_s[256], w1_s[256], b1_s[256], ts2[256];
    __shared__ int id_s[256];
    __shared__ unsigned scratch[SEG * 128 * 4]; // 16 KB: ranks / SA..BC / c-pack
    float* SA = (float*)scratch;
    float* SC = SA + SEG * 128;
    float* BA = SC + SEG * 128;
    float* BC = BA + SEG * 128;
    const int f = blockIdx.x, tid = threadIdx.x;

    if (tid < 256) {
        const float w = W1[f * H1D + tid];
        const float bb = b1[f * H1D + tid];
        w1_s[tid] = w;
        b1_s[tid] = bb;
        t_s[tid] = (w != 0.f) ? (-bb / w) : __builtin_inff();
    }
    __syncthreads();

    // ---- rank-sort ----
    {
        const int kq = tid >> 8, kk = tid & 255;
        const float tk = t_s[kk];
        int r = 0;
        const int k0 = kq * 64;
#pragma unroll 16
        for (int k2 = k0; k2 < k0 + 64; ++k2) {
            const float t2 = t_s[k2];
            r += (t2 < tk || (t2 == tk && k2 < kk)) ? 1 : 0;
        }
        scratch[kq * 256 + kk] = (unsigned)r;
    }
    __syncthreads();
    if (tid < 256) {
        const int r = (int)(scratch[tid] + scratch[256 + tid] +
                            scratch[512 + tid] + scratch[768 + tid]);
        ts2[r] = t_s[tid];
        id_s[r] = tid;
    }
    __syncthreads();

    const int seg = tid >> 7, n = tid & 127;
    const float* w2p = W2 + (size_t)f * H1D * H2D;

    // ---- Pass A: sorted walk, W2 values cached in registers ----
    float w2r[SEGLEN];                        // 32 VGPRs: replay buffer
    {
        float sa = 0.f, sc = 0.f, ba = 0.f, bc = 0.f;
#pragma unroll
        for (int ii = 0; ii < SEGLEN; ++ii) {
            const int kk = id_s[seg * SEGLEN + ii];
            const float ws = w1_s[kk], bs = b1_s[kk];
            const float w2s = w2p[kk * H2D + n];
            w2r[ii] = w2s;
            if (ws < 0.f) { ba += ws * w2s; bc += bs * w2s; }
            else if (ws == 0.f && bs > 0.f) bc += bs * w2s;
            const float dA = (ws > 0.f) ? ws : ((ws < 0.f) ? -ws : 0.f);
            const float dC = (ws > 0.f) ? bs : ((ws < 0.f) ? -bs : 0.f);
            sa += dA * w2s;
            sc += dC * w2s;
        }
        SA[seg * 128 + n] = sa; SC[seg * 128 + n] = sc;
        BA[seg * 128 + n] = ba; BC[seg * 128 + n] = bc;
    }
    __syncthreads();

    // ---- offsets -> registers (scratch reads complete after this) ----
    float baseA = 0.f, baseC = b2[f * H2D + n];
#pragma unroll
    for (int s = 0; s < SEG; ++s) {
        baseA += BA[s * 128 + n];
        baseC += BC[s * 128 + n];
    }
    float A = baseA, C = baseC;
    for (int s = 0; s < seg; ++s) {
        A += SA[s * 128 + n];
        C += SC[s * 128 + n];
    }
    __syncthreads();   // scratch reads done; cpack writes may begin

    // ---- E0: per-b search (strided x reads), pack into scratch.
    //      Global-x latency overlaps Pass B's pure-compute replay. ----
#pragma unroll
    for (int rd = 0; rd < 4; ++rd) {
        const int b = rd * 1024 + tid;
        const float xv = x[(size_t)b * FDIM + f];
        int c = 0;
#pragma unroll
        for (int s = 256; s >= 1; s >>= 1) {
            const int m = c + s;
            if (m <= 256 && ts2[m - 1] <= xv) c = m;
        }
        H16U hx;
        hx.h = (_Float16)xv;
        scratch[b] = (unsigned)c | ((unsigned)hx.u << 16);
    }

    // ---- Pass B: register replay (NO global loads), DPP-paired writes ----
    {
        const int pr = n >> 1;
        const bool wr = ((n & 1) == 0);
        if (seg == 0) {
            H16U ah, ch;
            ah.h = (_Float16)baseA;
            ch.h = (_Float16)baseC;
            const unsigned ao = (unsigned)DPP_GET_I(ah.u, 0xB1);
            const unsigned co = (unsigned)DPP_GET_I(ch.u, 0xB1);
            if (wr) {
                uint2 v;
                v.x = (unsigned)ah.u | (ao << 16);
                v.y = (unsigned)ch.u | (co << 16);
                *(uint2*)(rlds + pr * 2) = v;
            }
        }
#pragma unroll
        for (int ii = 0; ii < SEGLEN; ++ii) {
            const int i = seg * SEGLEN + ii + 1;    // rows 1..256
            const int kk = id_s[i - 1];
            const float ws = w1_s[kk], bs = b1_s[kk];
            const float w2s = w2r[ii];
            const float dA = (ws > 0.f) ? ws : ((ws < 0.f) ? -ws : 0.f);
            const float dC = (ws > 0.f) ? bs : ((ws < 0.f) ? -bs : 0.f);
            A += dA * w2s;
            C += dC * w2s;
            H16U ah, ch;
            ah.h = (_Float16)A;
            ch.h = (_Float16)C;
            const unsigned ao = (unsigned)DPP_GET_I(ah.u, 0xB1);
            const unsigned co = (unsigned)DPP_GET_I(ch.u, 0xB1);
            if (wr) {
                uint2 v;
                v.x = (unsigned)ah.u | (ao << 16);
                v.y = (unsigned)ch.u | (co << 16);
                *(uint2*)(rlds + i * ROW_U32 + pr * 2) = v;
            }
        }
    }
    __syncthreads();   // rows + cpack both visible

    // ---- E1: 16-lane groups; W3 from 2 coalesced float4 -> f16 regs;
    //      2 b128 + 1 scratch read per b; DPP-ror reduce on VALU ----
    const int grp = tid >> 4, gl = tid & 15;
    const float4 wva = *(const float4*)(W3 + f * H2D + 4 * gl);
    const float4 wvb = *(const float4*)(W3 + f * H2D + 64 + 4 * gl);
    U32H2 w3q0x, w3q0y, w3q1x, w3q1y;
    w3q0x.h[0] = (_Float16)wva.x; w3q0x.h[1] = (_Float16)wva.y;
    w3q0y.h[0] = (_Float16)wva.z; w3q0y.h[1] = (_Float16)wva.w;
    w3q1x.h[0] = (_Float16)wvb.x; w3q1x.h[1] = (_Float16)wvb.y;
    w3q1y.h[0] = (_Float16)wvb.z; w3q1y.h[1] = (_Float16)wvb.w;
    const half2v z2 = {(_Float16)0.f, (_Float16)0.f};
#pragma unroll 4
    for (int p = 0; p < 64; p += 2) {
        const int b0 = p * 64 + grp;
        const int b1i = (p + 1) * 64 + grp;
        const unsigned ci0 = scratch[b0];
        const unsigned ci1 = scratch[b1i];
        const unsigned* rp0 = rlds + (ci0 & 0xffffu) * ROW_U32;
        const unsigned* rp1 = rlds + (ci1 & 0xffffu) * ROW_U32;
        // issue all 4 b128 loads up front (ILP)
        const uint4 v00 = *(const uint4*)(rp0 + 4 * gl);
        const uint4 v01 = *(const uint4*)(rp0 + 4 * gl + 64);
        const uint4 v10 = *(const uint4*)(rp1 + 4 * gl);
        const uint4 v11 = *(const uint4*)(rp1 + 4 * gl + 64);
        U32H2 xv0, xv1;
        xv0.u = (ci0 >> 16) | (ci0 & 0xffff0000u);
        xv1.u = (ci1 >> 16) | (ci1 & 0xffff0000u);
        float c0a = 0.f, c1a = 0.f;
        {
            U32H2 a0, cc0, a1, cc1;
            a0.u = v00.x; cc0.u = v00.y; a1.u = v00.z; cc1.u = v00.w;
            half2v h0 = __builtin_elementwise_max(xv0.h * a0.h + cc0.h, z2);
            half2v h1 = __builtin_elementwise_max(xv0.h * a1.h + cc1.h, z2);
            c0a = __builtin_amdgcn_fdot2(h0, w3q0x.h, c0a, false);
            c0a = __builtin_amdgcn_fdot2(h1, w3q0y.h, c0a, false);
            a0.u = v01.x; cc0.u = v01.y; a1.u = v01.z; cc1.u = v01.w;
            h0 = __builtin_elementwise_max(xv0.h * a0.h + cc0.h, z2);
            h1 = __builtin_elementwise_max(xv0.h * a1.h + cc1.h, z2);
            c0a = __builtin_amdgcn_fdot2(h0, w3q1x.h, c0a, false);
            c0a = __builtin_amdgcn_fdot2(h1, w3q1y.h, c0a, false);
        }
        {
            U32H2 a0, cc0, a1, cc1;
            a0.u = v10.x; cc0.u = v10.y; a1.u = v10.z; cc1.u = v10.w;
            half2v h0 = __builtin_elementwise_max(xv1.h * a0.h + cc0.h, z2);
            half2v h1 = __builtin_elementwise_max(xv1.h * a1.h + cc1.h, z2);
            c1a = __builtin_amdgcn_fdot2(h0, w3q0x.h, c1a, false);
            c1a = __builtin_amdgcn_fdot2(h1, w3q0y.h, c1a, false);
            a0.u = v11.x; cc0.u = v11.y; a1.u = v11.z; cc1.u = v11.w;
            h0 = __builtin_elementwise_max(xv1.h * a0.h + cc0.h, z2);
            h1 = __builtin_elementwise_max(xv1.h * a1.h + cc1.h, z2);
            c1a = __builtin_amdgcn_fdot2(h0, w3q1x.h, c1a, false);
            c1a = __builtin_amdgcn_fdot2(h1, w3q1y.h, c1a, false);
        }
        // DPP reduce within each 16-lane row (VALU pipe); ror -> all lanes
        c0a = DPP_ADD_F(c0a, 0xB1);
        c0a = DPP_ADD_F(c0a, 0x4E);
        c0a = DPP_ADD_F(c0a, 0x124);
        c0a = DPP_ADD_F(c0a, 0x128);
        c1a = DPP_ADD_F(c1a, 0xB1);
        c1a = DPP_ADD_F(c1a, 0x4E);
        c1a = DPP_ADD_F(c1a, 0x124);
        c1a = DPP_ADD_F(c1a, 0x128);
        if (gl == 0) {
            partial[(size_t)f * BATCH + b0] = c0a;
            partial[(size_t)f * BATCH + b1i] = c1a;
        }
    }
}

// ---------------------------------------------------------------------------
// Final reduction over 256 per-feature partials + sum of b3.
// ---------------------------------------------------------------------------
__global__ __launch_bounds__(256) void reduce_out(const float* __restrict__ partial,
                                                  const float* __restrict__ b3,
                                                  float* __restrict__ out) {
    const int b = blockIdx.x * 256 + threadIdx.x;
    float v = 0.f;
    for (int p = 0; p < FDIM; ++p) v += partial[(size_t)p * BATCH + b];
    float sb3 = 0.f;
#pragma unroll 4
    for (int f4 = 0; f4 < FDIM; f4 += 4) {
        const float4 t = *(const float4*)(b3 + f4);
        sb3 += t.x + t.y + t.z + t.w;
    }
    out[b] = v + sb3;
}

extern "C" void kernel_launch(void* const* d_in, const int* in_sizes, int n_in,
                              void* d_out, int out_size, void* d_ws, size_t ws_size,
                              hipStream_t stream) {
    const float* x  = (const float*)d_in[0];
    const float* W1 = (const float*)d_in[1];
    const float* b1 = (const float*)d_in[2];
    const float* W2 = (const float*)d_in[3];
    const float* b2 = (const float*)d_in[4];
    const float* W3 = (const float*)d_in[5];
    const float* b3 = (const float*)d_in[6];

    float* partial = (float*)d_ws;
    const size_t need = (size_t)FDIM * BATCH * 4;
    if (ws_size < need) return;  // insufficient scratch; fail visibly

    coxnam_fused<<<256, 1024, DLDS_BYTES, stream>>>(W1, b1, W2, b2, x, W3,
                                                    partial);
    reduce_out<<<BATCH / 256, 256, 0, stream>>>(partial, b3, (float*)d_out);
}

// Round 27
// 68.119 us; speedup vs baseline: 1.0289x; 1.0289x over previous
//
#include <hip/hip_runtime.h>

#define FDIM  256
#define H1D   256
#define H2D   128
#define BATCH 4096

typedef _Float16 half2v __attribute__((ext_vector_type(2)));

#define ROW_U32    132                       // 64 (A,C) u32 pairs + 4 pad (16B-aligned rows)
#define NROWS      257
#define DLDS_U32   (NROWS * ROW_U32)         // 33,924
#define DLDS_BYTES (DLDS_U32 * 4)            // 135,696

#define SEG    8
#define SEGLEN 32

union U32H2 { unsigned u; half2v h; };
union H16U { _Float16 h; unsigned short u; };

// DPP helpers: cross-lane on the VALU pipe (not DS). bound_ctrl=true -> 0 fill.
#define DPP_ADD_F(v, ctrl)                                                   \
    ((v) + __int_as_float(__builtin_amdgcn_update_dpp(                       \
               0, __float_as_int(v), (ctrl), 0xf, 0xf, true)))
#define DPP_GET_I(x, ctrl)                                                   \
    __builtin_amdgcn_update_dpp(0, (int)(x), (ctrl), 0xf, 0xf, true)
// ctrl: quad_perm[1,0,3,2]=0xB1 (xor1), [2,3,0,1]=0x4E (xor2),
//       row_ror:4=0x124, row_ror:8=0x128 (rotation -> total in ALL lanes).

// ---------------------------------------------------------------------------
// Fused build+eval (R26 + explicit E1 software pipeline):
// E1's per-iteration 2-hop LDS chain (scratch -> row addr -> b128) was the
// last unhidden dependent chain: the compiler does NOT pipeline it under
// #pragma unroll (stayed at 64 VGPR under a 128 cap). Explicit named-var
// pipeline: scratch prefetched 2 pairs ahead, rows 1 pair ahead, ordered
// [rows p+2] -> [compute p] -> [DPP+store p] -> [rotate, scratch p+4]:
// every LDS hop gets a full compute phase of latency cover.
// ---------------------------------------------------------------------------
__global__ __launch_bounds__(1024, 4) void coxnam_fused(
    const float* __restrict__ W1, const float* __restrict__ b1,
    const float* __restrict__ W2, const float* __restrict__ b2,
    const float* __restrict__ x,  const float* __restrict__ W3,
    float* __restrict__ partial) {
    extern __shared__ unsigned rlds[];          // 33,924 u32 = 132.5 KB
    __shared__ float t_s[256], w1_s[256], b1_s[256], ts2[256];
    __shared__ int id_s[256];
    __shared__ unsigned scratch[SEG * 128 * 4]; // 16 KB: ranks / SA..BC / c-pack
    float* SA = (float*)scratch;
    float* SC = SA + SEG * 128;
    float* BA = SC + SEG * 128;
    float* BC = BA + SEG * 128;
    const int f = blockIdx.x, tid = threadIdx.x;

    if (tid < 256) {
        const float w = W1[f * H1D + tid];
        const float bb = b1[f * H1D + tid];
        w1_s[tid] = w;
        b1_s[tid] = bb;
        t_s[tid] = (w != 0.f) ? (-bb / w) : __builtin_inff();
    }
    __syncthreads();

    // ---- rank-sort ----
    {
        const int kq = tid >> 8, kk = tid & 255;
        const float tk = t_s[kk];
        int r = 0;
        const int k0 = kq * 64;
#pragma unroll 16
        for (int k2 = k0; k2 < k0 + 64; ++k2) {
            const float t2 = t_s[k2];
            r += (t2 < tk || (t2 == tk && k2 < kk)) ? 1 : 0;
        }
        scratch[kq * 256 + kk] = (unsigned)r;
    }
    __syncthreads();
    if (tid < 256) {
        const int r = (int)(scratch[tid] + scratch[256 + tid] +
                            scratch[512 + tid] + scratch[768 + tid]);
        ts2[r] = t_s[tid];
        id_s[r] = tid;
    }
    __syncthreads();

    const int seg = tid >> 7, n = tid & 127;
    const float* w2p = W2 + (size_t)f * H1D * H2D;

    // ---- Pass A: sorted walk, W2 values cached in registers ----
    float w2r[SEGLEN];                        // 32 VGPRs: replay buffer
    {
        float sa = 0.f, sc = 0.f, ba = 0.f, bc = 0.f;
#pragma unroll
        for (int ii = 0; ii < SEGLEN; ++ii) {
            const int kk = id_s[seg * SEGLEN + ii];
            const float ws = w1_s[kk], bs = b1_s[kk];
            const float w2s = w2p[kk * H2D + n];
            w2r[ii] = w2s;
            if (ws < 0.f) { ba += ws * w2s; bc += bs * w2s; }
            else if (ws == 0.f && bs > 0.f) bc += bs * w2s;
            const float dA = (ws > 0.f) ? ws : ((ws < 0.f) ? -ws : 0.f);
            const float dC = (ws > 0.f) ? bs : ((ws < 0.f) ? -bs : 0.f);
            sa += dA * w2s;
            sc += dC * w2s;
        }
        SA[seg * 128 + n] = sa; SC[seg * 128 + n] = sc;
        BA[seg * 128 + n] = ba; BC[seg * 128 + n] = bc;
    }
    __syncthreads();

    // ---- offsets -> registers (scratch reads complete after this) ----
    float baseA = 0.f, baseC = b2[f * H2D + n];
#pragma unroll
    for (int s = 0; s < SEG; ++s) {
        baseA += BA[s * 128 + n];
        baseC += BC[s * 128 + n];
    }
    float A = baseA, C = baseC;
    for (int s = 0; s < seg; ++s) {
        A += SA[s * 128 + n];
        C += SC[s * 128 + n];
    }
    __syncthreads();   // scratch reads done; cpack writes may begin

    // ---- E0: hoisted x loads (4 independent), then searches, pack ----
    {
        float xvr[4];
#pragma unroll
        for (int rd = 0; rd < 4; ++rd)
            xvr[rd] = x[(size_t)(rd * 1024 + tid) * FDIM + f];
#pragma unroll
        for (int rd = 0; rd < 4; ++rd) {
            const float xv = xvr[rd];
            int c = 0;
#pragma unroll
            for (int s = 256; s >= 1; s >>= 1) {
                const int m = c + s;
                if (m <= 256 && ts2[m - 1] <= xv) c = m;
            }
            H16U hx;
            hx.h = (_Float16)xv;
            scratch[rd * 1024 + tid] = (unsigned)c | ((unsigned)hx.u << 16);
        }
    }

    // ---- Pass B: register replay (NO global loads), DPP-paired writes ----
    {
        const int pr = n >> 1;
        const bool wr = ((n & 1) == 0);
        if (seg == 0) {
            H16U ah, ch;
            ah.h = (_Float16)baseA;
            ch.h = (_Float16)baseC;
            const unsigned ao = (unsigned)DPP_GET_I(ah.u, 0xB1);
            const unsigned co = (unsigned)DPP_GET_I(ch.u, 0xB1);
            if (wr) {
                uint2 v;
                v.x = (unsigned)ah.u | (ao << 16);
                v.y = (unsigned)ch.u | (co << 16);
                *(uint2*)(rlds + pr * 2) = v;
            }
        }
#pragma unroll
        for (int ii = 0; ii < SEGLEN; ++ii) {
            const int i = seg * SEGLEN + ii + 1;    // rows 1..256
            const int kk = id_s[i - 1];
            const float ws = w1_s[kk], bs = b1_s[kk];
            const float w2s = w2r[ii];
            const float dA = (ws > 0.f) ? ws : ((ws < 0.f) ? -ws : 0.f);
            const float dC = (ws > 0.f) ? bs : ((ws < 0.f) ? -bs : 0.f);
            A += dA * w2s;
            C += dC * w2s;
            H16U ah, ch;
            ah.h = (_Float16)A;
            ch.h = (_Float16)C;
            const unsigned ao = (unsigned)DPP_GET_I(ah.u, 0xB1);
            const unsigned co = (unsigned)DPP_GET_I(ch.u, 0xB1);
            if (wr) {
                uint2 v;
                v.x = (unsigned)ah.u | (ao << 16);
                v.y = (unsigned)ch.u | (co << 16);
                *(uint2*)(rlds + i * ROW_U32 + pr * 2) = v;
            }
        }
    }
    __syncthreads();   // rows + cpack both visible

    // ---- E1: explicit software pipeline.
    //      scratch 2 pairs ahead, rows 1 pair ahead:
    //      [rows p+2] -> [compute p] -> [DPP+store p] -> [scratch p+4] ----
    const int grp = tid >> 4, gl = tid & 15;
    const float4 wva = *(const float4*)(W3 + f * H2D + 4 * gl);
    const float4 wvb = *(const float4*)(W3 + f * H2D + 64 + 4 * gl);
    U32H2 w3q0x, w3q0y, w3q1x, w3q1y;
    w3q0x.h[0] = (_Float16)wva.x; w3q0x.h[1] = (_Float16)wva.y;
    w3q0y.h[0] = (_Float16)wva.z; w3q0y.h[1] = (_Float16)wva.w;
    w3q1x.h[0] = (_Float16)wvb.x; w3q1x.h[1] = (_Float16)wvb.y;
    w3q1y.h[0] = (_Float16)wvb.z; w3q1y.h[1] = (_Float16)wvb.w;
    const half2v z2 = {(_Float16)0.f, (_Float16)0.f};

    // prologue: scratch pairs 0,1 + rows; scratch pair 2 prefetch
    unsigned sA0 = scratch[grp];
    unsigned sA1 = scratch[64 + grp];
    const unsigned* r0p = rlds + (sA0 & 0xffffu) * ROW_U32 + 4 * gl;
    const unsigned* r1p = rlds + (sA1 & 0xffffu) * ROW_U32 + 4 * gl;
    uint4 v00 = *(const uint4*)(r0p);
    uint4 v01 = *(const uint4*)(r0p + 64);
    uint4 v10 = *(const uint4*)(r1p);
    uint4 v11 = *(const uint4*)(r1p + 64);
    unsigned sB0 = scratch[128 + grp];
    unsigned sB1 = scratch[192 + grp];

#pragma unroll 4
    for (int p = 0; p < 64; p += 2) {
        // stage 1: load NEXT pair's rows (addresses from sB, fetched earlier)
        uint4 n00, n01, n10, n11;
        if (p + 2 < 64) {
            const unsigned* q0 = rlds + (sB0 & 0xffffu) * ROW_U32 + 4 * gl;
            const unsigned* q1 = rlds + (sB1 & 0xffffu) * ROW_U32 + 4 * gl;
            n00 = *(const uint4*)(q0);
            n01 = *(const uint4*)(q0 + 64);
            n10 = *(const uint4*)(q1);
            n11 = *(const uint4*)(q1 + 64);
        }
        // stage 2: compute CURRENT pair
        U32H2 xv0, xv1;
        xv0.u = (sA0 >> 16) | (sA0 & 0xffff0000u);
        xv1.u = (sA1 >> 16) | (sA1 & 0xffff0000u);
        float c0a = 0.f, c1a = 0.f;
        {
            U32H2 a0, cc0, a1, cc1;
            a0.u = v00.x; cc0.u = v00.y; a1.u = v00.z; cc1.u = v00.w;
            half2v h0 = __builtin_elementwise_max(xv0.h * a0.h + cc0.h, z2);
            half2v h1 = __builtin_elementwise_max(xv0.h * a1.h + cc1.h, z2);
            c0a = __builtin_amdgcn_fdot2(h0, w3q0x.h, c0a, false);
            c0a = __builtin_amdgcn_fdot2(h1, w3q0y.h, c0a, false);
            a0.u = v01.x; cc0.u = v01.y; a1.u = v01.z; cc1.u = v01.w;
            h0 = __builtin_elementwise_max(xv0.h * a0.h + cc0.h, z2);
            h1 = __builtin_elementwise_max(xv0.h * a1.h + cc1.h, z2);
            c0a = __builtin_amdgcn_fdot2(h0, w3q1x.h, c0a, false);
            c0a = __builtin_amdgcn_fdot2(h1, w3q1y.h, c0a, false);
        }
        {
            U32H2 a0, cc0, a1, cc1;
            a0.u = v10.x; cc0.u = v10.y; a1.u = v10.z; cc1.u = v10.w;
            half2v h0 = __builtin_elementwise_max(xv1.h * a0.h + cc0.h, z2);
            half2v h1 = __builtin_elementwise_max(xv1.h * a1.h + cc1.h, z2);
            c1a = __builtin_amdgcn_fdot2(h0, w3q0x.h, c1a, false);
            c1a = __builtin_amdgcn_fdot2(h1, w3q0y.h, c1a, false);
            a0.u = v11.x; cc0.u = v11.y; a1.u = v11.z; cc1.u = v11.w;
            h0 = __builtin_elementwise_max(xv1.h * a0.h + cc0.h, z2);
            h1 = __builtin_elementwise_max(xv1.h * a1.h + cc1.h, z2);
            c1a = __builtin_amdgcn_fdot2(h0, w3q1x.h, c1a, false);
            c1a = __builtin_amdgcn_fdot2(h1, w3q1y.h, c1a, false);
        }
        // stage 3: DPP reduce + store current
        c0a = DPP_ADD_F(c0a, 0xB1);
        c0a = DPP_ADD_F(c0a, 0x4E);
        c0a = DPP_ADD_F(c0a, 0x124);
        c0a = DPP_ADD_F(c0a, 0x128);
        c1a = DPP_ADD_F(c1a, 0xB1);
        c1a = DPP_ADD_F(c1a, 0x4E);
        c1a = DPP_ADD_F(c1a, 0x124);
        c1a = DPP_ADD_F(c1a, 0x128);
        if (gl == 0) {
            partial[(size_t)f * BATCH + p * 64 + grp] = c0a;
            partial[(size_t)f * BATCH + (p + 1) * 64 + grp] = c1a;
        }
        // stage 4: rotate; prefetch scratch 2 pairs ahead
        sA0 = sB0;
        sA1 = sB1;
        if (p + 4 < 64) {
            sB0 = scratch[(p + 4) * 64 + grp];
            sB1 = scratch[(p + 5) * 64 + grp];
        }
        v00 = n00; v01 = n01; v10 = n10; v11 = n11;
    }
}

// ---------------------------------------------------------------------------
// Final reduction over 256 per-feature partials + sum of b3.
// ---------------------------------------------------------------------------
__global__ __launch_bounds__(256) void reduce_out(const float* __restrict__ partial,
                                                  const float* __restrict__ b3,
                                                  float* __restrict__ out) {
    const int b = blockIdx.x * 256 + threadIdx.x;
    float v = 0.f;
    for (int p = 0; p < FDIM; ++p) v += partial[(size_t)p * BATCH + b];
    float sb3 = 0.f;
#pragma unroll 4
    for (int f4 = 0; f4 < FDIM; f4 += 4) {
        const float4 t = *(const float4*)(b3 + f4);
        sb3 += t.x + t.y + t.z + t.w;
    }
    out[b] = v + sb3;
}

extern "C" void kernel_launch(void* const* d_in, const int* in_sizes, int n_in,
                              void* d_out, int out_size, void* d_ws, size_t ws_size,
                              hipStream_t stream) {
    const float* x  = (const float*)d_in[0];
    const float* W1 = (const float*)d_in[1];
    const float* b1 = (const float*)d_in[2];
    const float* W2 = (const float*)d_in[3];
    const float* b2 = (const float*)d_in[4];
    const float* W3 = (const float*)d_in[5];
    const float* b3 = (const float*)d_in[6];

    float* partial = (float*)d_ws;
    const size_t need = (size_t)FDIM * BATCH * 4;
    if (ws_size < need) return;  // insufficient scratch; fail visibly

    coxnam_fused<<<256, 1024, DLDS_BYTES, stream>>>(W1, b1, W2, b2, x, W3,
                                                    partial);
    reduce_out<<<BATCH / 256, 256, 0, stream>>>(partial, b3, (float*)d_out);
}